// Round 11
// baseline (115.697 us; speedup 1.0000x reference)
//
#include <hip/hip_runtime.h>
#include <hip/hip_bf16.h>

typedef float f32x4 __attribute__((ext_vector_type(4)));
typedef short short8_t __attribute__((ext_vector_type(8)));

// fp32 -> bf16 round-to-nearest-even, two at a time, pure bit ops
__device__ __forceinline__ unsigned int cvt2(float lo, float hi) {
    unsigned int ul = __builtin_bit_cast(unsigned int, lo);
    unsigned int uh = __builtin_bit_cast(unsigned int, hi);
    ul += 0x7FFFu + ((ul >> 16) & 1u);
    uh += 0x7FFFu + ((uh >> 16) & 1u);
    return (ul >> 16) | (uh & 0xFFFF0000u);
}

__device__ __forceinline__ float sq4(f32x4 v, float acc) {
    acc = fmaf(v[0], v[0], acc); acc = fmaf(v[1], v[1], acc);
    acc = fmaf(v[2], v[2], acc); acc = fmaf(v[3], v[3], acc);
    return acc;
}

__device__ __forceinline__ float dot4(f32x4 a, f32x4 b, float acc) {
    acc = fmaf(a[0], b[0], acc); acc = fmaf(a[1], b[1], acc);
    acc = fmaf(a[2], b[2], acc); acc = fmaf(a[3], b[3], acc);
    return acc;
}

__device__ __forceinline__ short8_t pk8(f32x4 a, f32x4 b) {
    union { short8_t s; unsigned int u[4]; } w;
    w.u[0] = cvt2(a[0], a[1]); w.u[1] = cvt2(a[2], a[3]);
    w.u[2] = cvt2(b[0], b[1]); w.u[3] = cvt2(b[2], b[3]);
    return w.s;
}

// ====== prep: fp32 -> bf16 in MFMA-FRAGMENT order + row/col stats ======
// Fragment layout (16B granules): slot = (row16*16 + kc)*64 + ko*16 + rl
//   where row16=row/16, rl=row%16, kc=k/32, ko=(k%32)/8.
// A wave in the GEMM reads slot base+lane -> lane l holds row (l&15),
// k-offset (l>>4)*8 : exactly the mfma_f32_16x16x32_bf16 operand mapping
// (verified by 5 passing rounds of the LDS variant).
__global__ __launch_bounds__(256)
void prep_kernel(const float* __restrict__ X, const float* __restrict__ P,
                 const float* __restrict__ A, const float* __restrict__ S,
                 short* __restrict__ Xf, short* __restrict__ Pf, short* __restrict__ Af,
                 float* __restrict__ x2a, float* __restrict__ paa, float* __restrict__ Ba,
                 float* __restrict__ rBana, float* __restrict__ esla, int N, int O)
{
    const int D = 512;
    const int w    = blockIdx.x * 4 + (threadIdx.x >> 6);
    const int lane = threadIdx.x & 63;
    if (w < N) {
        const float* row = X + (size_t)w * D + lane * 8;
        f32x4 u0 = *(const f32x4*)row;
        f32x4 u1 = *(const f32x4*)(row + 4);
        size_t sl = ((size_t)(w >> 4) * 16 + (lane >> 2)) * 64 + (size_t)(lane & 3) * 16 + (w & 15);
        *(short8_t*)(Xf + sl * 8) = pk8(u0, u1);
        float s = sq4(u1, sq4(u0, 0.f));
        #pragma unroll
        for (int m = 1; m < 64; m <<= 1) s += __shfl_xor(s, m, 64);
        if (lane == 0) x2a[w] = s;
    } else if (w < N + O) {
        const int col = w - N;
        const float* prow = P + (size_t)col * D + lane * 8;
        const float* arow = A + (size_t)col * D + lane * 8;
        f32x4 p0 = *(const f32x4*)prow, p1 = *(const f32x4*)(prow + 4);
        f32x4 a0 = *(const f32x4*)arow, a1 = *(const f32x4*)(arow + 4);
        size_t sl = ((size_t)(col >> 4) * 16 + (lane >> 2)) * 64 + (size_t)(lane & 3) * 16 + (col & 15);
        *(short8_t*)(Pf + sl * 8) = pk8(p0, p1);
        *(short8_t*)(Af + sl * 8) = pk8(a0, a1);
        float sp  = sq4(p1, sq4(p0, 0.f));
        float sa  = sq4(a1, sq4(a0, 0.f));
        float spa = dot4(p1, a1, dot4(p0, a0, 0.f));
        #pragma unroll
        for (int m = 1; m < 64; m <<= 1) {
            sp += __shfl_xor(sp, m, 64);
            sa += __shfl_xor(sa, m, 64);
            spa += __shfl_xor(spa, m, 64);
        }
        if (lane == 0) {
            float B  = 1.f - sp;
            float an = fmaxf(__builtin_amdgcn_sqrtf(sa), 1e-15f);
            paa[col]   = spa;
            Ba[col]    = B;
            rBana[col] = __builtin_amdgcn_rcpf(fmaxf(B * an, 1e-30f));
            esla[col]  = 0.69314718055994531f * expf(S[col]);
        }
    }
}

// ====== main: LDS-free dual-GEMM, fragments loaded global->VGPR ======
// 128x128 tile, 4 waves (2x2), wave tile 64x64. NO barriers/LDS in K-loop.
// Per K=32 step: 4 A-frag + 4+4 B-frag dwordx4 loads (1KB coalesced each)
// feeding 32 MFMA. Epilogue: LDS bounce (two 64-row passes), f32x4 stores.
#define BM2 128
#define BN2 128

__global__ __launch_bounds__(256, 2)
void mobius_gemm_kernel(const short* __restrict__ Xb, const short* __restrict__ Pb,
                        const short* __restrict__ Ab,
                        const float* __restrict__ x2a, const float* __restrict__ paa,
                        const float* __restrict__ Ba, const float* __restrict__ rBana,
                        const float* __restrict__ esla,
                        float* __restrict__ out, int N, int O)
{
    __shared__ float ob[64 * 132];                 // epilogue bounce only (33792 B)

    const int nwg = gridDim.x;                     // %8==0 guaranteed by host
    const int q   = nwg >> 3;
    const int swz = (blockIdx.x & 7) * q + (blockIdx.x >> 3);
    const int ncol = O / BN2;                      // col-fastest for L2 x-panel sharing
    const int brow = swz / ncol, bcol = swz % ncol;
    const int n0 = brow * BM2, o0 = bcol * BN2;

    const int tid = threadIdx.x, lane = tid & 63, wid = tid >> 6;
    const int wr = wid >> 1, wc = wid & 1;         // wave tile 64x64

    f32x4 accP[4][4], accA[4][4];
    #pragma unroll
    for (int m = 0; m < 4; m++)
        #pragma unroll
        for (int n = 0; n < 4; n++) { accP[m][n] = (f32x4)0.f; accA[m][n] = (f32x4)0.f; }

    const short8_t* Xf = (const short8_t*)Xb;      // 16B granules
    const short8_t* Pf = (const short8_t*)Pb;
    const short8_t* Af = (const short8_t*)Ab;

    // wave fragment bases (in 16B slots): frag m/n adds m*1024; K-step adds 64
    const size_t abase = ((size_t)((n0 >> 4) + wr * 4) * 16) * 64 + lane;
    const size_t bbase = ((size_t)((o0 >> 4) + wc * 4) * 16) * 64 + lane;

    #pragma unroll 4
    for (int st = 0; st < 16; ++st) {              // K=32 per step
        const size_t ko = (size_t)st * 64;
        short8_t af[4], bp[4], ba[4];
        #pragma unroll
        for (int m = 0; m < 4; m++) af[m] = Xf[abase + (size_t)m * 1024 + ko];
        #pragma unroll
        for (int n = 0; n < 4; n++) {
            bp[n] = Pf[bbase + (size_t)n * 1024 + ko];
            ba[n] = Af[bbase + (size_t)n * 1024 + ko];
        }
        #pragma unroll
        for (int m = 0; m < 4; m++)
            #pragma unroll
            for (int n = 0; n < 4; n++) {
                accP[m][n] = __builtin_amdgcn_mfma_f32_16x16x32_bf16(af[m], bp[n], accP[m][n], 0, 0, 0);
                accA[m][n] = __builtin_amdgcn_mfma_f32_16x16x32_bf16(af[m], ba[n], accA[m][n], 0, 0, 0);
            }
    }

    // ---- epilogue: two-pass LDS bounce (64 rows each) -> coalesced f32x4 stores ----
    const int cl_ = lane & 15, g = lane >> 4;
    float pac[4], Bc[4], rB[4], es[4];
    #pragma unroll
    for (int n = 0; n < 4; n++) {
        int col = o0 + wc * 64 + n * 16 + cl_;
        pac[n] = paa[col]; Bc[n] = Ba[col]; rB[n] = rBana[col]; es[n] = esla[col];
    }
    #pragma unroll
    for (int p = 0; p < 2; ++p) {
        if (wr == p) {
            #pragma unroll
            for (int m = 0; m < 4; m++) {
                #pragma unroll
                for (int r = 0; r < 4; r++) {
                    const int lrow = m * 16 + g * 4 + r;
                    const float x2  = x2a[n0 + p * 64 + lrow];
                    const float ap1 = 1.f + x2;
                    const float zs  = 2.f * __builtin_amdgcn_rcpf(fmaxf(1.f - x2, 1e-30f));
                    #pragma unroll
                    for (int n = 0; n < 4; n++) {
                        float xp = accP[m][n][r];
                        float xa = accA[m][n][r];
                        float Acf = ap1 - (xp + xp);                    // A = 1 - 2xp + x2
                        float num = fmaf(Bc[n], xa, -(Acf * pac[n]));   // B*xa - A*pa
                        float z   = num * zs * rB[n];
                        float az  = fabsf(z);
                        float wv  = az + __builtin_amdgcn_sqrtf(fmaf(z, z, 1.f));
                        float l   = __builtin_amdgcn_logf(wv);
                        ob[lrow * 132 + wc * 64 + n * 16 + cl_] = copysignf(l, z) * es[n];
                    }
                }
            }
        }
        __syncthreads();
        #pragma unroll
        for (int s = 0; s < 8; ++s) {
            int row = s * 8 + (tid >> 5), c = (tid & 31) * 4;
            f32x4 v = *(const f32x4*)(ob + row * 132 + c);
            *(f32x4*)(out + (size_t)(n0 + p * 64 + row) * O + o0 + c) = v;
        }
        if (p == 0) __syncthreads();
    }
}

// ================= fallback (known-passing single kernel, R5) ===============
#define BM 128
#define BN 128
#define BK 64
#define PAD 8
#define LDT (BK + PAD)

__global__ __launch_bounds__(256, 2)
void mobius_d2p_kernel(const float* __restrict__ X, const float* __restrict__ P,
                       const float* __restrict__ A, const float* __restrict__ S,
                       float* __restrict__ out, int N, int O, int D)
{
    __shared__ short xs[BM][LDT];
    __shared__ short ps[BM][LDT];
    __shared__ short as_[BM][LDT];
    __shared__ float x2p[BM][2];
    __shared__ float p2p[BM][2];
    __shared__ float pap[BM][2];
    __shared__ float a2p[BM][2];

    const int nwg = gridDim.x;
    int swz = blockIdx.x;
    if ((nwg & 7) == 0) {
        int q = nwg >> 3;
        swz = (blockIdx.x & 7) * q + (blockIdx.x >> 3);
    }
    const int ncol = O / BN;
    const int brow = swz / ncol;
    const int bcol = swz % ncol;
    const int n0 = brow * BM;
    const int o0 = bcol * BN;

    const int tid  = threadIdx.x;
    const int lane = tid & 63;
    const int wid  = tid >> 6;
    const int wr   = wid >> 1;
    const int wc   = wid & 1;

    const int srow = tid >> 1;
    const int sseg = (tid & 1) * 32;

    const float* xg = X + (size_t)(n0 + srow) * D + sseg;
    const float* pg = P + (size_t)(o0 + srow) * D + sseg;
    const float* ag = A + (size_t)(o0 + srow) * D + sseg;

    float accx2 = 0.f, accp2 = 0.f, accpa = 0.f, acca2 = 0.f;

    f32x4 accP[4][4], accA[4][4];
    #pragma unroll
    for (int i = 0; i < 4; i++)
        #pragma unroll
        for (int j = 0; j < 4; j++) { accP[i][j] = (f32x4)0.f; accA[i][j] = (f32x4)0.f; }

    const int frow_a = wr * 64 + (lane & 15);
    const int frow_b = wc * 64 + (lane & 15);
    const int fk     = (lane >> 4) * 8;

    const int nk = D / BK;
    for (int ks = 0; ks < nk; ++ks) {
        const float* xr = xg + ks * BK;
        const float* pr = pg + ks * BK;
        const float* ar = ag + ks * BK;

        #pragma unroll
        for (int j = 0; j < 4; j++) {
            f32x4 u0 = *(const f32x4*)(xr + j * 8);
            f32x4 u1 = *(const f32x4*)(xr + j * 8 + 4);
            accx2 = sq4(u0, accx2); accx2 = sq4(u1, accx2);
            *(short8_t*)&xs[srow][sseg + j * 8] = pk8(u0, u1);
        }
        #pragma unroll
        for (int j = 0; j < 4; j++) {
            f32x4 u0 = *(const f32x4*)(pr + j * 8);
            f32x4 u1 = *(const f32x4*)(pr + j * 8 + 4);
            f32x4 v0 = *(const f32x4*)(ar + j * 8);
            f32x4 v1 = *(const f32x4*)(ar + j * 8 + 4);
            accp2 = sq4(u0, accp2); accp2 = sq4(u1, accp2);
            acca2 = sq4(v0, acca2); acca2 = sq4(v1, acca2);
            accpa = dot4(u0, v0, accpa); accpa = dot4(u1, v1, accpa);
            *(short8_t*)&ps[srow][sseg + j * 8] = pk8(u0, u1);
            *(short8_t*)&as_[srow][sseg + j * 8] = pk8(v0, v1);
        }
        __syncthreads();

        #pragma unroll
        for (int kk = 0; kk < 2; ++kk) {
            const int kof = kk * 32 + fk;
            short8_t af[4], bp[4], ba[4];
            #pragma unroll
            for (int m = 0; m < 4; m++) af[m] = *(const short8_t*)&xs[frow_a + m * 16][kof];
            #pragma unroll
            for (int n = 0; n < 4; n++) {
                bp[n] = *(const short8_t*)&ps[frow_b + n * 16][kof];
                ba[n] = *(const short8_t*)&as_[frow_b + n * 16][kof];
            }
            #pragma unroll
            for (int m = 0; m < 4; m++)
                #pragma unroll
                for (int n = 0; n < 4; n++) {
                    accP[m][n] = __builtin_amdgcn_mfma_f32_16x16x32_bf16(af[m], bp[n], accP[m][n], 0, 0, 0);
                    accA[m][n] = __builtin_amdgcn_mfma_f32_16x16x32_bf16(af[m], ba[n], accA[m][n], 0, 0, 0);
                }
        }
        __syncthreads();
    }

    x2p[srow][tid & 1] = accx2;
    p2p[srow][tid & 1] = accp2;
    pap[srow][tid & 1] = accpa;
    a2p[srow][tid & 1] = acca2;
    __syncthreads();

    const int cl = lane & 15;
    const int g  = lane >> 4;

    float pac[4], Bcv[4], rBan[4], esl[4];
    #pragma unroll
    for (int n = 0; n < 4; n++) {
        int col = wc * 64 + n * 16 + cl;
        float p2 = p2p[col][0] + p2p[col][1];
        float pa = pap[col][0] + pap[col][1];
        float a2 = a2p[col][0] + a2p[col][1];
        float B  = 1.f - p2;
        float an = fmaxf(__builtin_amdgcn_sqrtf(a2), 1e-15f);
        pac[n] = pa; Bcv[n] = B;
        rBan[n] = __builtin_amdgcn_rcpf(fmaxf(B * an, 1e-30f));
        esl[n]  = 0.69314718055994531f * expf(S[o0 + col]);
    }
    float x2r[16];
    #pragma unroll
    for (int m = 0; m < 4; m++)
        #pragma unroll
        for (int r = 0; r < 4; r++) {
            int row = wr * 64 + m * 16 + g * 4 + r;
            x2r[m * 4 + r] = x2p[row][0] + x2p[row][1];
        }

    #pragma unroll
    for (int m = 0; m < 4; m++) {
        #pragma unroll
        for (int r = 0; r < 4; r++) {
            const int row = wr * 64 + m * 16 + g * 4 + r;
            const float x2  = x2r[m * 4 + r];
            const float ap1 = 1.f + x2;
            const float zs  = 2.f * __builtin_amdgcn_rcpf(fmaxf(1.f - x2, 1e-30f));
            float* orow = out + (size_t)(n0 + row) * O + o0 + wc * 64 + cl;
            #pragma unroll
            for (int n = 0; n < 4; n++) {
                float xp = accP[m][n][r];
                float xa = accA[m][n][r];
                float Ac = ap1 - (xp + xp);
                float num = fmaf(Bcv[n], xa, -(Ac * pac[n]));
                float z   = num * zs * rBan[n];
                float az = fabsf(z);
                float w  = az + __builtin_amdgcn_sqrtf(fmaf(z, z, 1.f));
                float l  = __builtin_amdgcn_logf(w);
                orow[n * 16] = copysignf(l, z) * esl[n];
            }
        }
    }
}

extern "C" void kernel_launch(void* const* d_in, const int* in_sizes, int n_in,
                              void* d_out, int out_size, void* d_ws, size_t ws_size,
                              hipStream_t stream) {
    const float* X = (const float*)d_in[0];
    const float* P = (const float*)d_in[1];
    const float* A = (const float*)d_in[2];
    const float* S = (const float*)d_in[3];
    float* out = (float*)d_out;

    const int O = in_sizes[3];
    const int D = in_sizes[1] / O;
    const int N = in_sizes[0] / D;

    // workspace layout
    size_t offP  = (size_t)N * D * 2;
    size_t offA  = offP + (size_t)O * D * 2;
    size_t offx2 = offA + (size_t)O * D * 2;
    size_t offpa = offx2 + (size_t)N * 4;
    size_t offB  = offpa + (size_t)O * 4;
    size_t offrB = offB + (size_t)O * 4;
    size_t offes = offrB + (size_t)O * 4;
    size_t need  = offes + (size_t)O * 4;

    const bool fast = (ws_size >= need) && D == 512 &&
                      (N % BM2 == 0) && (O % BN2 == 0) && (N % 16 == 0) && (O % 16 == 0) &&
                      (((N / BM2) * (O / BN2)) % 8 == 0) && ((N + O) % 4 == 0);

    if (fast) {
        char* ws = (char*)d_ws;
        short* Xf = (short*)ws;
        short* Pf = (short*)(ws + offP);
        short* Af = (short*)(ws + offA);
        float* x2a = (float*)(ws + offx2);
        float* paa = (float*)(ws + offpa);
        float* Ba  = (float*)(ws + offB);
        float* rBa = (float*)(ws + offrB);
        float* esl = (float*)(ws + offes);

        prep_kernel<<<dim3((N + O) / 4), dim3(256), 0, stream>>>(
            X, P, A, S, Xf, Pf, Af, x2a, paa, Ba, rBa, esl, N, O);
        mobius_gemm_kernel<<<dim3((N / BM2) * (O / BN2)), dim3(256), 0, stream>>>(
            Xf, Pf, Af, x2a, paa, Ba, rBa, esl, out, N, O);
    } else {
        const int nwg = (N / BM) * (O / BN);
        mobius_d2p_kernel<<<dim3(nwg), dim3(256), 0, stream>>>(X, P, A, S, out, N, O, D);
    }
}

// Round 12
// 111.116 us; speedup vs baseline: 1.0412x; 1.0412x over previous
//
#include <hip/hip_runtime.h>
#include <hip/hip_bf16.h>

typedef float f32x4 __attribute__((ext_vector_type(4)));
typedef short short8_t __attribute__((ext_vector_type(8)));

// fp32 -> bf16 round-to-nearest-even, two at a time, pure bit ops
__device__ __forceinline__ unsigned int cvt2(float lo, float hi) {
    unsigned int ul = __builtin_bit_cast(unsigned int, lo);
    unsigned int uh = __builtin_bit_cast(unsigned int, hi);
    ul += 0x7FFFu + ((ul >> 16) & 1u);
    uh += 0x7FFFu + ((uh >> 16) & 1u);
    return (ul >> 16) | (uh & 0xFFFF0000u);
}

__device__ __forceinline__ float sq4(f32x4 v, float acc) {
    acc = fmaf(v[0], v[0], acc); acc = fmaf(v[1], v[1], acc);
    acc = fmaf(v[2], v[2], acc); acc = fmaf(v[3], v[3], acc);
    return acc;
}

__device__ __forceinline__ float dot4(f32x4 a, f32x4 b, float acc) {
    acc = fmaf(a[0], b[0], acc); acc = fmaf(a[1], b[1], acc);
    acc = fmaf(a[2], b[2], acc); acc = fmaf(a[3], b[3], acc);
    return acc;
}

__device__ __forceinline__ short8_t pk8(f32x4 a, f32x4 b) {
    union { short8_t s; unsigned int u[4]; } w;
    w.u[0] = cvt2(a[0], a[1]); w.u[1] = cvt2(a[2], a[3]);
    w.u[2] = cvt2(b[0], b[1]); w.u[3] = cvt2(b[2], b[3]);
    return w.s;
}

__device__ __forceinline__ void gload16(const void* g, void* l) {
    __builtin_amdgcn_global_load_lds(
        (const __attribute__((address_space(1))) unsigned int*)g,
        (__attribute__((address_space(3))) unsigned int*)l, 16, 0, 0);
}

// ================= prep (R8-proven): fp32 -> bf16 row-major + stats ===============
__global__ __launch_bounds__(256)
void prep_kernel(const float* __restrict__ X, const float* __restrict__ P,
                 const float* __restrict__ A, const float* __restrict__ S,
                 short* __restrict__ Xb, short* __restrict__ Pb, short* __restrict__ Ab,
                 float* __restrict__ x2a, float* __restrict__ paa, float* __restrict__ Ba,
                 float* __restrict__ rBana, float* __restrict__ esla, int N, int O)
{
    const int D = 512;
    const int w    = blockIdx.x * 4 + (threadIdx.x >> 6);
    const int lane = threadIdx.x & 63;
    if (w < N) {
        const float* row = X + (size_t)w * D + lane * 8;
        f32x4 u0 = *(const f32x4*)row;
        f32x4 u1 = *(const f32x4*)(row + 4);
        *(short8_t*)(Xb + (size_t)w * D + lane * 8) = pk8(u0, u1);
        float s = sq4(u1, sq4(u0, 0.f));
        #pragma unroll
        for (int m = 1; m < 64; m <<= 1) s += __shfl_xor(s, m, 64);
        if (lane == 0) x2a[w] = s;
    } else if (w < N + O) {
        const int col = w - N;
        const float* prow = P + (size_t)col * D + lane * 8;
        const float* arow = A + (size_t)col * D + lane * 8;
        f32x4 p0 = *(const f32x4*)prow, p1 = *(const f32x4*)(prow + 4);
        f32x4 a0 = *(const f32x4*)arow, a1 = *(const f32x4*)(arow + 4);
        *(short8_t*)(Pb + (size_t)col * D + lane * 8) = pk8(p0, p1);
        *(short8_t*)(Ab + (size_t)col * D + lane * 8) = pk8(a0, a1);
        float sp  = sq4(p1, sq4(p0, 0.f));
        float sa  = sq4(a1, sq4(a0, 0.f));
        float spa = dot4(p1, a1, dot4(p0, a0, 0.f));
        #pragma unroll
        for (int m = 1; m < 64; m <<= 1) {
            sp += __shfl_xor(sp, m, 64);
            sa += __shfl_xor(sa, m, 64);
            spa += __shfl_xor(spa, m, 64);
        }
        if (lane == 0) {
            float B  = 1.f - sp;
            float an = fmaxf(__builtin_amdgcn_sqrtf(sa), 1e-15f);
            paa[col]   = spa;
            Ba[col]    = B;
            rBana[col] = __builtin_amdgcn_rcpf(fmaxf(B * an, 1e-30f));
            esla[col]  = 0.69314718055994531f * expf(S[col]);
        }
    }
}

// ====== main: 256x128 tile, BK=64, 512 threads (8 waves 4Mx2N), dbuf 2x64KB ======
// Pipeline per K-tile: __syncthreads at TOP (drains loads issued one full compute
// phase ago -> cheap), then issue tile t+1's 8 global_load_lds, then 2 kk-phases of
// {12 ds_read_b128 -> setprio(1) -> 32 MFMA -> setprio(0)}. One barrier per tile.
// XOR chunk swizzle (ch ^ (row&7)) pre-applied on global src, re-applied on ds_read.
#define BM2 256
#define BN2 128
#define BK2 64
#define BUFB 65536

__device__ __forceinline__ void stage256(const char* Xc, const char* Pc, const char* Ac,
                                         char* buf, int n0, int o0, int ks, int tid) {
    const size_t kb = (size_t)ks * (BK2 * 2);      // 128 B per K-step
    #pragma unroll
    for (int s = 0; s < 4; ++s) {                  // X: 256 rows x 8 chunks = 2048
        int cl = s * 512 + tid, row = cl >> 3, ch = cl & 7;
        gload16(Xc + (size_t)(n0 + row) * 1024 + kb + (size_t)((ch ^ (row & 7)) << 4),
                buf + cl * 16);
    }
    #pragma unroll
    for (int s = 0; s < 2; ++s) {                  // P/A: 128 rows x 8 chunks = 1024
        int cl = s * 512 + tid, row = cl >> 3, ch = cl & 7;
        size_t go = (size_t)(o0 + row) * 1024 + kb + (size_t)((ch ^ (row & 7)) << 4);
        gload16(Pc + go, buf + 32768 + cl * 16);
        gload16(Ac + go, buf + 49152 + cl * 16);
    }
}

__global__ __launch_bounds__(512, 2)
void mobius_gemm_kernel(const short* __restrict__ Xb, const short* __restrict__ Pb,
                        const short* __restrict__ Ab,
                        const float* __restrict__ x2a, const float* __restrict__ paa,
                        const float* __restrict__ Ba, const float* __restrict__ rBana,
                        const float* __restrict__ esla,
                        float* __restrict__ out, int N, int O)
{
    extern __shared__ __align__(16) char smem[];   // 131072 B dynamic

    const int nwg = gridDim.x;                     // %8==0 guaranteed by host
    const int q   = nwg >> 3;
    const int swz = (blockIdx.x & 7) * q + (blockIdx.x >> 3);
    const int ncol = O / BN2;                      // col-fastest for L2 x-panel sharing
    const int brow = swz / ncol, bcol = swz % ncol;
    const int n0 = brow * BM2, o0 = bcol * BN2;

    const int tid = threadIdx.x, lane = tid & 63, wid = tid >> 6;
    const int wr = wid >> 1, wc = wid & 1;         // 4M x 2N waves, wave tile 64x64

    f32x4 accP[4][4], accA[4][4];
    #pragma unroll
    for (int m = 0; m < 4; m++)
        #pragma unroll
        for (int n = 0; n < 4; n++) { accP[m][n] = (f32x4)0.f; accA[m][n] = (f32x4)0.f; }

    const char* Xc = (const char*)Xb;
    const char* Pc = (const char*)Pb;
    const char* Ac = (const char*)Ab;

    const int fr = lane & 15;
    const int fo = (lane >> 4) << 4;               // k-chunk byte offset within 64B half

    stage256(Xc, Pc, Ac, smem, n0, o0, 0, tid);

    int cur = 0;
    #pragma unroll 1
    for (int t = 0; t < 8; ++t) {
        __syncthreads();                           // drains tile t's loads (issued ~1 tile ago)
        if (t < 7)
            stage256(Xc, Pc, Ac, smem + (cur ^ 1) * BUFB, n0, o0, t + 1, tid);
        __builtin_amdgcn_sched_barrier(0);         // keep stage-issue ahead of compute

        const char* xs = smem + cur * BUFB;
        const char* ps = xs + 32768;
        const char* as = xs + 49152;

        #pragma unroll
        for (int kk = 0; kk < 2; ++kk) {
            const int kx = (kk * 64 + fo) ^ ((lane & 7) << 4);
            short8_t af[4], bp[4], ba[4];
            #pragma unroll
            for (int m = 0; m < 4; m++)
                af[m] = *(const short8_t*)(xs + ((wr * 64 + m * 16 + fr) << 7) + kx);
            #pragma unroll
            for (int n = 0; n < 4; n++) {
                bp[n] = *(const short8_t*)(ps + ((wc * 64 + n * 16 + fr) << 7) + kx);
                ba[n] = *(const short8_t*)(as + ((wc * 64 + n * 16 + fr) << 7) + kx);
            }
            __builtin_amdgcn_s_setprio(1);
            #pragma unroll
            for (int m = 0; m < 4; m++)
                #pragma unroll
                for (int n = 0; n < 4; n++) {
                    accP[m][n] = __builtin_amdgcn_mfma_f32_16x16x32_bf16(af[m], bp[n], accP[m][n], 0, 0, 0);
                    accA[m][n] = __builtin_amdgcn_mfma_f32_16x16x32_bf16(af[m], ba[n], accA[m][n], 0, 0, 0);
                }
            __builtin_amdgcn_s_setprio(0);
        }
        cur ^= 1;
    }
    __syncthreads();

    // ---- epilogue: two passes of 128 rows via LDS bounce -> coalesced f32x4 stores ----
    const int cl_ = lane & 15, g = lane >> 4;
    float pac[4], Bc[4], rB[4], es[4];
    #pragma unroll
    for (int n = 0; n < 4; n++) {
        int col = o0 + wc * 64 + n * 16 + cl_;
        pac[n] = paa[col]; Bc[n] = Ba[col]; rB[n] = rBana[col]; es[n] = esla[col];
    }
    float* ob = (float*)smem;                      // [128][132] f32 = 67584 B <= 128KB
    #pragma unroll
    for (int p = 0; p < 2; ++p) {
        if ((wr >> 1) == p) {
            #pragma unroll
            for (int m = 0; m < 4; m++) {
                #pragma unroll
                for (int r = 0; r < 4; r++) {
                    const int lrow = (wr & 1) * 64 + m * 16 + g * 4 + r;
                    const float x2  = x2a[n0 + p * 128 + lrow];
                    const float ap1 = 1.f + x2;
                    const float zs  = 2.f * __builtin_amdgcn_rcpf(fmaxf(1.f - x2, 1e-30f));
                    #pragma unroll
                    for (int n = 0; n < 4; n++) {
                        float xp = accP[m][n][r];
                        float xa = accA[m][n][r];
                        float Acf = ap1 - (xp + xp);                    // A = 1 - 2xp + x2
                        float num = fmaf(Bc[n], xa, -(Acf * pac[n]));   // B*xa - A*pa
                        float z   = num * zs * rB[n];
                        float az  = fabsf(z);
                        float wv  = az + __builtin_amdgcn_sqrtf(fmaf(z, z, 1.f));
                        float l   = __builtin_amdgcn_logf(wv);
                        ob[lrow * 132 + wc * 64 + n * 16 + cl_] = copysignf(l, z) * es[n];
                    }
                }
            }
        }
        __syncthreads();
        #pragma unroll
        for (int s = 0; s < 8; ++s) {
            int row = s * 16 + (tid >> 5), c = (tid & 31) * 4;
            f32x4 v = *(const f32x4*)(ob + row * 132 + c);
            *(f32x4*)(out + (size_t)(n0 + p * 128 + row) * O + o0 + c) = v;
        }
        if (p == 0) __syncthreads();
    }
}

// ================= fallback (known-passing single kernel, R5) ===============
#define BM 128
#define BN 128
#define BK 64
#define PAD 8
#define LDT (BK + PAD)

__global__ __launch_bounds__(256, 2)
void mobius_d2p_kernel(const float* __restrict__ X, const float* __restrict__ P,
                       const float* __restrict__ A, const float* __restrict__ S,
                       float* __restrict__ out, int N, int O, int D)
{
    __shared__ short xs[BM][LDT];
    __shared__ short ps[BM][LDT];
    __shared__ short as_[BM][LDT];
    __shared__ float x2p[BM][2];
    __shared__ float p2p[BM][2];
    __shared__ float pap[BM][2];
    __shared__ float a2p[BM][2];

    const int nwg = gridDim.x;
    int swz = blockIdx.x;
    if ((nwg & 7) == 0) {
        int q = nwg >> 3;
        swz = (blockIdx.x & 7) * q + (blockIdx.x >> 3);
    }
    const int ncol = O / BN;
    const int brow = swz / ncol;
    const int bcol = swz % ncol;
    const int n0 = brow * BM;
    const int o0 = bcol * BN;

    const int tid  = threadIdx.x;
    const int lane = tid & 63;
    const int wid  = tid >> 6;
    const int wr   = wid >> 1;
    const int wc   = wid & 1;

    const int srow = tid >> 1;
    const int sseg = (tid & 1) * 32;

    const float* xg = X + (size_t)(n0 + srow) * D + sseg;
    const float* pg = P + (size_t)(o0 + srow) * D + sseg;
    const float* ag = A + (size_t)(o0 + srow) * D + sseg;

    float accx2 = 0.f, accp2 = 0.f, accpa = 0.f, acca2 = 0.f;

    f32x4 accP[4][4], accA[4][4];
    #pragma unroll
    for (int i = 0; i < 4; i++)
        #pragma unroll
        for (int j = 0; j < 4; j++) { accP[i][j] = (f32x4)0.f; accA[i][j] = (f32x4)0.f; }

    const int frow_a = wr * 64 + (lane & 15);
    const int frow_b = wc * 64 + (lane & 15);
    const int fk     = (lane >> 4) * 8;

    const int nk = D / BK;
    for (int ks = 0; ks < nk; ++ks) {
        const float* xr = xg + ks * BK;
        const float* pr = pg + ks * BK;
        const float* ar = ag + ks * BK;

        #pragma unroll
        for (int j = 0; j < 4; j++) {
            f32x4 u0 = *(const f32x4*)(xr + j * 8);
            f32x4 u1 = *(const f32x4*)(xr + j * 8 + 4);
            accx2 = sq4(u0, accx2); accx2 = sq4(u1, accx2);
            *(short8_t*)&xs[srow][sseg + j * 8] = pk8(u0, u1);
        }
        #pragma unroll
        for (int j = 0; j < 4; j++) {
            f32x4 u0 = *(const f32x4*)(pr + j * 8);
            f32x4 u1 = *(const f32x4*)(pr + j * 8 + 4);
            f32x4 v0 = *(const f32x4*)(ar + j * 8);
            f32x4 v1 = *(const f32x4*)(ar + j * 8 + 4);
            accp2 = sq4(u0, accp2); accp2 = sq4(u1, accp2);
            acca2 = sq4(v0, acca2); acca2 = sq4(v1, acca2);
            accpa = dot4(u0, v0, accpa); accpa = dot4(u1, v1, accpa);
            *(short8_t*)&ps[srow][sseg + j * 8] = pk8(u0, u1);
            *(short8_t*)&as_[srow][sseg + j * 8] = pk8(v0, v1);
        }
        __syncthreads();

        #pragma unroll
        for (int kk = 0; kk < 2; ++kk) {
            const int kof = kk * 32 + fk;
            short8_t af[4], bp[4], ba[4];
            #pragma unroll
            for (int m = 0; m < 4; m++) af[m] = *(const short8_t*)&xs[frow_a + m * 16][kof];
            #pragma unroll
            for (int n = 0; n < 4; n++) {
                bp[n] = *(const short8_t*)&ps[frow_b + n * 16][kof];
                ba[n] = *(const short8_t*)&as_[frow_b + n * 16][kof];
            }
            #pragma unroll
            for (int m = 0; m < 4; m++)
                #pragma unroll
                for (int n = 0; n < 4; n++) {
                    accP[m][n] = __builtin_amdgcn_mfma_f32_16x16x32_bf16(af[m], bp[n], accP[m][n], 0, 0, 0);
                    accA[m][n] = __builtin_amdgcn_mfma_f32_16x16x32_bf16(af[m], ba[n], accA[m][n], 0, 0, 0);
                }
        }
        __syncthreads();
    }

    x2p[srow][tid & 1] = accx2;
    p2p[srow][tid & 1] = accp2;
    pap[srow][tid & 1] = accpa;
    a2p[srow][tid & 1] = acca2;
    __syncthreads();

    const int cl = lane & 15;
    const int g  = lane >> 4;

    float pac[4], Bcv[4], rBan[4], esl[4];
    #pragma unroll
    for (int n = 0; n < 4; n++) {
        int col = wc * 64 + n * 16 + cl;
        float p2 = p2p[col][0] + p2p[col][1];
        float pa = pap[col][0] + pap[col][1];
        float a2 = a2p[col][0] + a2p[col][1];
        float B  = 1.f - p2;
        float an = fmaxf(__builtin_amdgcn_sqrtf(a2), 1e-15f);
        pac[n] = pa; Bcv[n] = B;
        rBan[n] = __builtin_amdgcn_rcpf(fmaxf(B * an, 1e-30f));
        esl[n]  = 0.69314718055994531f * expf(S[o0 + col]);
    }
    float x2r[16];
    #pragma unroll
    for (int m = 0; m < 4; m++)
        #pragma unroll
        for (int r = 0; r < 4; r++) {
            int row = wr * 64 + m * 16 + g * 4 + r;
            x2r[m * 4 + r] = x2p[row][0] + x2p[row][1];
        }

    #pragma unroll
    for (int m = 0; m < 4; m++) {
        #pragma unroll
        for (int r = 0; r < 4; r++) {
            const int row = wr * 64 + m * 16 + g * 4 + r;
            const float x2  = x2r[m * 4 + r];
            const float ap1 = 1.f + x2;
            const float zs  = 2.f * __builtin_amdgcn_rcpf(fmaxf(1.f - x2, 1e-30f));
            float* orow = out + (size_t)(n0 + row) * O + o0 + wc * 64 + cl;
            #pragma unroll
            for (int n = 0; n < 4; n++) {
                float xp = accP[m][n][r];
                float xa = accA[m][n][r];
                float Ac = ap1 - (xp + xp);
                float num = fmaf(Bcv[n], xa, -(Ac * pac[n]));
                float z   = num * zs * rBan[n];
                float az = fabsf(z);
                float w  = az + __builtin_amdgcn_sqrtf(fmaf(z, z, 1.f));
                float l  = __builtin_amdgcn_logf(w);
                orow[n * 16] = copysignf(l, z) * esl[n];
            }
        }
    }
}

extern "C" void kernel_launch(void* const* d_in, const int* in_sizes, int n_in,
                              void* d_out, int out_size, void* d_ws, size_t ws_size,
                              hipStream_t stream) {
    const float* X = (const float*)d_in[0];
    const float* P = (const float*)d_in[1];
    const float* A = (const float*)d_in[2];
    const float* S = (const float*)d_in[3];
    float* out = (float*)d_out;

    const int O = in_sizes[3];
    const int D = in_sizes[1] / O;
    const int N = in_sizes[0] / D;

    // workspace layout
    size_t offP  = (size_t)N * D * 2;
    size_t offA  = offP + (size_t)O * D * 2;
    size_t offx2 = offA + (size_t)O * D * 2;
    size_t offpa = offx2 + (size_t)N * 4;
    size_t offB  = offpa + (size_t)O * 4;
    size_t offrB = offB + (size_t)O * 4;
    size_t offes = offrB + (size_t)O * 4;
    size_t need  = offes + (size_t)O * 4;

    bool fast = (ws_size >= need) && D == 512 &&
                (N % BM2 == 0) && (O % BN2 == 0) &&
                (((N / BM2) * (O / BN2)) % 8 == 0) && ((N + O) % 4 == 0);

    if (fast) {
        hipError_t e = hipFuncSetAttribute(
            (const void*)mobius_gemm_kernel,
            hipFuncAttributeMaxDynamicSharedMemorySize, 2 * BUFB);
        if (e != hipSuccess) fast = false;
    }

    if (fast) {
        char* ws = (char*)d_ws;
        short* Xb = (short*)ws;
        short* Pb = (short*)(ws + offP);
        short* Ab = (short*)(ws + offA);
        float* x2a = (float*)(ws + offx2);
        float* paa = (float*)(ws + offpa);
        float* Ba  = (float*)(ws + offB);
        float* rBa = (float*)(ws + offrB);
        float* esl = (float*)(ws + offes);

        prep_kernel<<<dim3((N + O) / 4), dim3(256), 0, stream>>>(
            X, P, A, S, Xb, Pb, Ab, x2a, paa, Ba, rBa, esl, N, O);
        mobius_gemm_kernel<<<dim3((N / BM2) * (O / BN2)), dim3(512), 2 * BUFB, stream>>>(
            Xb, Pb, Ab, x2a, paa, Ba, rBa, esl, out, N, O);
    } else {
        const int nwg = (N / BM) * (O / BN);
        mobius_d2p_kernel<<<dim3(nwg), dim3(256), 0, stream>>>(X, P, A, S, out, N, O, D);
    }
}